// Round 5
// baseline (346.429 us; speedup 1.0000x reference)
//
#include <hip/hip_runtime.h>

#define BATCH 16
#define T_LEN 2048
#define E_DIM 768
#define E4 (E_DIM / 4)        // 192 float4 per row
#define N_SENT 32
#define S_LEN 64
#define NCHUNK 64             // T chunks of 32 rows
#define ROWS_PER_CHUNK (T_LEN / NCHUNK)   // 32
#define CNT_STRIDE 16         // ints -> 64 B per batch counter (own cacheline)

typedef float nf4 __attribute__((ext_vector_type(4)));   // native vec for NT builtins

// -------- Kernel A: pool partials + (last block per batch) index computation ----
// grid (BATCH, NCHUNK), block 256 (4 waves; pool uses threads 0..191).
// Phase 1: block (b,tc) sums rows [tc*32, tc*32+32) of batch b -> partial4.
// Release: threadfence -> atomicAdd on padded per-batch counter (round-2-verified
// visibility pattern, but NO consumer spin -- the kernel boundary syncs gather).
// Phase 2 (only the 64th-arriving block of each batch): acquire fence, reduce the
// 64 partials (L2/L3-warm), tiny matmul, write sidx/eidx. Absorbs the old 16-block
// compute_idx dispatch (which was ~100% launch/drain overhead).
__global__ __launch_bounds__(256) void fused_pool_idx(
    const float4* __restrict__ in4,
    const float*  __restrict__ W,
    const float*  __restrict__ bias,
    float4* __restrict__ partial4,
    int*    __restrict__ cnt,
    int*    __restrict__ sidx, int* __restrict__ eidx)
{
    const int tid = threadIdx.x;
    const int b   = blockIdx.x;
    const int tc  = blockIdx.y;
    __shared__ int amLast;

    if (tid < E4) {
        const float4* p = in4 + ((size_t)b * T_LEN + (size_t)tc * ROWS_PER_CHUNK) * E4 + tid;
        float4 s = make_float4(0.f, 0.f, 0.f, 0.f);
#pragma unroll 8
        for (int t = 0; t < ROWS_PER_CHUNK; ++t) {
            float4 v = p[(size_t)t * E4];
            s.x += v.x; s.y += v.y; s.z += v.z; s.w += v.w;
        }
        partial4[((size_t)tc * BATCH + b) * E4 + tid] = s;
    }
    __threadfence();            // release: this thread's partial stores visible
    __syncthreads();            // all threads' fences precede the counter bump
    if (tid == 0) {
        int old = atomicAdd(&cnt[b * CNT_STRIDE], 1);   // device-scope, padded line
        amLast = (old == NCHUNK - 1) ? 1 : 0;
    }
    __syncthreads();
    if (!amLast) return;

    // ---- last block of batch b: mean -> pooled @ W + bias -> indices ----
    __threadfence();            // acquire: fresh view of all partials
    __shared__ float pooled[E_DIM];
    __shared__ float colsum[4][2 * N_SENT];
    __shared__ int   offi[2 * N_SENT];

    if (tid < E4) {
        float4 s = make_float4(0.f, 0.f, 0.f, 0.f);
#pragma unroll 8
        for (int pc = 0; pc < NCHUNK; ++pc) {
            float4 v = partial4[((size_t)pc * BATCH + b) * E4 + tid];
            s.x += v.x; s.y += v.y; s.z += v.z; s.w += v.w;
        }
        const float inv = 1.0f / (float)T_LEN;
        ((float4*)pooled)[tid] = make_float4(s.x * inv, s.y * inv, s.z * inv, s.w * inv);
    }
    __syncthreads();

    // tid -> (quarter q, column c). Lanes share q -> pooled reads broadcast;
    // consecutive c -> W reads coalesced (W is [768][64] row-major).
    {
        const int c = tid & 63;
        const int q = tid >> 6;
        float acc = 0.f;
        const float* pb = pooled + q * 192;
        const float* Wq = W + (size_t)q * 192 * (2 * N_SENT) + c;
#pragma unroll 8
        for (int e = 0; e < 192; ++e) acc += pb[e] * Wq[(size_t)e * (2 * N_SENT)];
        colsum[q][c] = acc;
    }
    __syncthreads();

    if (tid < 2 * N_SENT) {
        float o = bias[tid] + colsum[0][tid] + colsum[1][tid] + colsum[2][tid] + colsum[3][tid];
        // clip to [0, 63] then truncate (nonneg -> floor), matching astype(int32)
        float cl = fminf(fmaxf(o, 0.f), (float)(S_LEN - 1));
        offi[tid] = (int)cl;
    }
    __syncthreads();

    if (tid < N_SENT) {
        const int so   = offi[tid];
        const int eo   = offi[N_SENT + tid];
        const int base = tid * S_LEN;
        int si = min(base + so, T_LEN - S_LEN);            // clip(base+so, 0, T-L), so>=0
        int ei = min(max(base + S_LEN + eo, si), T_LEN);   // clip(base+L+eo, si, T)
        sidx[b * N_SENT + tid] = si;                        // kernel boundary publishes
        eidx[b * N_SENT + tid] = ei;
    }
}

// -------- Kernel B: gather rows (or zeros) -- unchanged, at write-bound floor ----
// grid = B*S*2 = 1024 blocks x 256 threads (4 waves). Block owns half a sentence
// (32 rows); wave q copies rows [q*8, q*8+8), 3 float4 per lane per row -> 24
// independent load/store pairs per lane. si/ei block-uniform -> scalar loads.
// NT stores: write-once output streams past L2, keeping input resident for reads.
__global__ __launch_bounds__(256) void gather_rows(const float4* __restrict__ in4,
                                                   const int* __restrict__ sidx,
                                                   const int* __restrict__ eidx,
                                                   float4* __restrict__ out4) {
    const int blk  = blockIdx.x;
    const int half = blk & 1;              // which 32-row half of the sentence
    const int s    = (blk >> 1) & (N_SENT - 1);
    const int b    = blk >> 6;
    const int lane = threadIdx.x & 63;
    const int q    = threadIdx.x >> 6;     // wave id 0..3

    const int si  = sidx[b * N_SENT + s];
    const int ei  = eidx[b * N_SENT + s];
    const int len = ei - si;

    const float4* src = in4  + ((size_t)b * T_LEN + si) * E4 + lane;
    float4*       dst = out4 + (((size_t)b * N_SENT + s) * S_LEN) * E4 + lane;
    const float4 z = make_float4(0.f, 0.f, 0.f, 0.f);

#pragma unroll 4
    for (int k = 0; k < 8; ++k) {
        const int j = half * 32 + q * 8 + k;   // row within sentence, wave-uniform
        float4 v0 = z, v1 = z, v2 = z;
        if (j < len) {                          // si+j <= 2047 always (ei <= T)
            const float4* sp = src + (size_t)j * E4;
            v0 = sp[0]; v1 = sp[64]; v2 = sp[128];
        }
        nf4* dp = (nf4*)(dst + (size_t)j * E4);
        __builtin_nontemporal_store(*(const nf4*)&v0, dp);        // always write (poisoned)
        __builtin_nontemporal_store(*(const nf4*)&v1, dp + 64);
        __builtin_nontemporal_store(*(const nf4*)&v2, dp + 128);
    }
}

extern "C" void kernel_launch(void* const* d_in, const int* in_sizes, int n_in,
                              void* d_out, int out_size, void* d_ws, size_t ws_size,
                              hipStream_t stream) {
    const float4* in4 = (const float4*)d_in[0];  // [16, 2048, 768]
    const float*  W   = (const float*)d_in[1];   // [768, 64]
    const float*  bias= (const float*)d_in[2];   // [64]
    float4* out4 = (float4*)d_out;               // [16, 32, 64, 768]

    const size_t partialBytes = (size_t)NCHUNK * BATCH * E4 * sizeof(float4); // 3 MB
    float4* partial4 = (float4*)d_ws;
    int* cnt  = (int*)((char*)d_ws + partialBytes);
    int* sidx = cnt + BATCH * CNT_STRIDE;
    int* eidx = sidx + BATCH * N_SENT;

    // workspace is poisoned each iteration: zero the 16 padded counters (1 KB)
    hipMemsetAsync(cnt, 0, (size_t)BATCH * CNT_STRIDE * sizeof(int), stream);

    fused_pool_idx<<<dim3(BATCH, NCHUNK), 256, 0, stream>>>(in4, W, bias,
                                                            partial4, cnt, sidx, eidx);
    gather_rows<<<dim3(BATCH * N_SENT * 2), 256, 0, stream>>>(in4, sidx, eidx, out4);
}

// Round 7
// 237.832 us; speedup vs baseline: 1.4566x; 1.4566x over previous
//
#include <hip/hip_runtime.h>

#define BATCH 16
#define T_LEN 2048
#define E_DIM 768
#define E4 (E_DIM / 4)        // 192 float4 per row
#define N_SENT 32
#define S_LEN 64
#define NCHUNK 32             // T chunks of 64 rows (round-0 baseline config)
#define ROWS_PER_CHUNK (T_LEN / NCHUNK)   // 64

typedef float nf4 __attribute__((ext_vector_type(4)));   // native vec for NT builtins

// -------- Kernel 1: partial column sums over T (round-0 baseline, at HBM floor) ----
// grid (BATCH, NCHUNK), block 192 (3 waves). Each block sums 64 rows of one batch.
__global__ void pool_partial(const float4* __restrict__ in4, float4* __restrict__ partial4) {
    const int tx = threadIdx.x;            // float4 index within row
    const int b  = blockIdx.x;
    const int tc = blockIdx.y;
    const float4* p = in4 + ((size_t)b * T_LEN + (size_t)tc * ROWS_PER_CHUNK) * E4 + tx;
    float4 s = make_float4(0.f, 0.f, 0.f, 0.f);
#pragma unroll 8
    for (int t = 0; t < ROWS_PER_CHUNK; ++t) {
        float4 v = p[(size_t)t * E4];
        s.x += v.x; s.y += v.y; s.z += v.z; s.w += v.w;
    }
    partial4[((size_t)tc * BATCH + b) * E4 + tx] = s;
}

// -------- Kernel 2: per-block index preamble + gather --------
// grid = B*S*2 = 1024 blocks x 256 threads. Block (b, s, half) redundantly computes
// ITS OWN sentence's (si, ei) from the partials (L2-warm, 98 KB/block), then gathers.
// Cross-block sync = the kernel boundary (cheap), NOT device fences (190 us, round 5).
// FP order of the index math replicates the old compute_idx bit-exactly:
//   pooled[e] = (sum over tc=0..31 in order) * inv ; per column: 4 sequential
//   quarter-sums over e, then bias + q0 + q1 + q2 + q3 -> clamp -> trunc.
__global__ __launch_bounds__(256) void gather_idx_rows(
    const float4* __restrict__ in4,
    const float4* __restrict__ partial4,
    const float*  __restrict__ W,
    const float*  __restrict__ bias,
    float4* __restrict__ out4)
{
    const int blk  = blockIdx.x;
    const int half = blk & 1;              // which 32-row half of the sentence
    const int s    = (blk >> 1) & (N_SENT - 1);
    const int b    = blk >> 6;
    const int tid  = threadIdx.x;
    const int lane = tid & 63;
    const int q    = tid >> 6;             // wave id 0..3

    __shared__ float pooled[E_DIM];
    __shared__ int   sie[2];               // [0]=start offset, [1]=end offset

    // ---- preamble 1: rebuild pooled row for batch b (threads 0..191) ----
    if (tid < E4) {
        float4 acc = make_float4(0.f, 0.f, 0.f, 0.f);
#pragma unroll 8
        for (int tc = 0; tc < NCHUNK; ++tc) {          // same order as compute_idx
            float4 v = partial4[((size_t)tc * BATCH + b) * E4 + tid];
            acc.x += v.x; acc.y += v.y; acc.z += v.z; acc.w += v.w;
        }
        const float inv = 1.0f / (float)T_LEN;
        ((float4*)pooled)[tid] = make_float4(acc.x * inv, acc.y * inv, acc.z * inv, acc.w * inv);
    }
    __syncthreads();

    // ---- preamble 2: two 768-length dots, exact old FP order (threads 0,1) ----
    if (tid < 2) {
        const int c = s + tid * N_SENT;    // tid 0 -> start col s, tid 1 -> end col s+32
        float qacc[4];
#pragma unroll
        for (int qq = 0; qq < 4; ++qq) {   // 4 sequential quarter-sums, as before
            float acc = 0.f;
            const float* pb = pooled + qq * 192;
            const float* Wq = W + (size_t)qq * 192 * (2 * N_SENT) + c;
#pragma unroll 8
            for (int e = 0; e < 192; ++e) acc += pb[e] * Wq[(size_t)e * (2 * N_SENT)];
            qacc[qq] = acc;
        }
        float o  = bias[c] + qacc[0] + qacc[1] + qacc[2] + qacc[3];
        float cl = fminf(fmaxf(o, 0.f), (float)(S_LEN - 1));
        sie[tid] = (int)cl;                // nonneg -> trunc == floor == astype(int32)
    }
    __syncthreads();

    // ---- index math (uniform across block, same as old compute_idx tail) ----
    const int so   = sie[0];
    const int eo   = sie[1];
    const int base = s * S_LEN;
    const int si   = min(base + so, T_LEN - S_LEN);          // clip(base+so, 0, T-L)
    const int ei   = min(max(base + S_LEN + eo, si), T_LEN); // clip(base+L+eo, si, T)
    const int len  = ei - si;

    // ---- gather: 32 rows (this half); wave q rows [q*8, q*8+8), 3 float4/lane ----
    const float4* src = in4  + ((size_t)b * T_LEN + si) * E4 + lane;
    float4*       dst = out4 + (((size_t)b * N_SENT + s) * S_LEN) * E4 + lane;
    const float4 z = make_float4(0.f, 0.f, 0.f, 0.f);

#pragma unroll 4
    for (int k = 0; k < 8; ++k) {
        const int j = half * 32 + q * 8 + k;   // row within sentence, wave-uniform
        float4 v0 = z, v1 = z, v2 = z;
        if (j < len) {                          // si+j <= 2047 always (ei <= T)
            const float4* sp = src + (size_t)j * E4;
            v0 = sp[0]; v1 = sp[64]; v2 = sp[128];
        }
        nf4* dp = (nf4*)(dst + (size_t)j * E4);
        __builtin_nontemporal_store(*(const nf4*)&v0, dp);        // always write (poisoned)
        __builtin_nontemporal_store(*(const nf4*)&v1, dp + 64);
        __builtin_nontemporal_store(*(const nf4*)&v2, dp + 128);
    }
}

extern "C" void kernel_launch(void* const* d_in, const int* in_sizes, int n_in,
                              void* d_out, int out_size, void* d_ws, size_t ws_size,
                              hipStream_t stream) {
    const float4* in4 = (const float4*)d_in[0];  // [16, 2048, 768]
    const float*  W   = (const float*)d_in[1];   // [768, 64]
    const float*  bias= (const float*)d_in[2];   // [64]
    float4* out4 = (float4*)d_out;               // [16, 32, 64, 768]

    float4* partial4 = (float4*)d_ws;            // NCHUNK*BATCH*E4 float4 = 1.5 MB

    pool_partial<<<dim3(BATCH, NCHUNK), 192, 0, stream>>>(in4, partial4);
    gather_idx_rows<<<dim3(BATCH * N_SENT * 2), 256, 0, stream>>>(
        in4, partial4, W, bias, out4);
}

// Round 8
// 204.105 us; speedup vs baseline: 1.6973x; 1.1652x over previous
//
#include <hip/hip_runtime.h>

#define BATCH 16
#define T_LEN 2048
#define E_DIM 768
#define E4 (E_DIM / 4)        // 192 float4 per row
#define N_SENT 32
#define S_LEN 64
#define NCHUNK 32             // T chunks of 64 rows
#define ROWS_PER_CHUNK (T_LEN / NCHUNK)   // 64

// -------- Kernel 1: partial column sums over T, float4-vectorized --------
// grid (BATCH, NCHUNK), block 192 (3 waves). Each block sums 64 rows of one batch.
// Measured at HBM cold-read floor (~17 us vs 15.2 floor).
__global__ void pool_partial(const float4* __restrict__ in4, float4* __restrict__ partial4) {
    const int tx = threadIdx.x;            // float4 index within row
    const int b  = blockIdx.x;
    const int tc = blockIdx.y;
    const float4* p = in4 + ((size_t)b * T_LEN + (size_t)tc * ROWS_PER_CHUNK) * E4 + tx;
    float4 s = make_float4(0.f, 0.f, 0.f, 0.f);
#pragma unroll 8
    for (int t = 0; t < ROWS_PER_CHUNK; ++t) {
        float4 v = p[(size_t)t * E4];
        s.x += v.x; s.y += v.y; s.z += v.z; s.w += v.w;
    }
    partial4[((size_t)tc * BATCH + b) * E4 + tx] = s;
}

// -------- Kernel 2: finish mean, tiny matmul, index computation --------
// grid BATCH blocks, 256 threads each. ~3-5 us as its own dispatch; every attempt
// to absorb it elsewhere cost more than it saved (fences: +190 us, round 5;
// per-gather-block preamble: +30 us, round 7). It stays a dispatch.
__global__ void compute_idx(const float4* __restrict__ partial4,
                            const float* __restrict__ W,
                            const float* __restrict__ bias,
                            int* __restrict__ sidx, int* __restrict__ eidx) {
    __shared__ float pooled[E_DIM];
    __shared__ float colsum[4][2 * N_SENT];
    __shared__ int   offi[2 * N_SENT];
    const int b   = blockIdx.x;
    const int tid = threadIdx.x;

    if (tid < E4) {
        float4 s = make_float4(0.f, 0.f, 0.f, 0.f);
#pragma unroll
        for (int tc = 0; tc < NCHUNK; ++tc) {
            float4 v = partial4[((size_t)tc * BATCH + b) * E4 + tid];
            s.x += v.x; s.y += v.y; s.z += v.z; s.w += v.w;
        }
        const float inv = 1.0f / (float)T_LEN;
        ((float4*)pooled)[tid] = make_float4(s.x * inv, s.y * inv, s.z * inv, s.w * inv);
    }
    __syncthreads();

    // tid -> (quarter q, column c). Lanes share q -> pooled reads broadcast;
    // consecutive c -> W reads coalesced (W is [768][64] row-major).
    const int c = tid & 63;
    const int q = tid >> 6;
    float acc = 0.f;
    const float* pb = pooled + q * 192;
    const float* Wq = W + (size_t)q * 192 * (2 * N_SENT) + c;
#pragma unroll 8
    for (int e = 0; e < 192; ++e) acc += pb[e] * Wq[(size_t)e * (2 * N_SENT)];
    colsum[q][c] = acc;
    __syncthreads();

    if (tid < 2 * N_SENT) {
        float o = bias[tid] + colsum[0][tid] + colsum[1][tid] + colsum[2][tid] + colsum[3][tid];
        // clip to [0, 63] then truncate (nonneg -> floor), matching astype(int32)
        float cl = fminf(fmaxf(o, 0.f), (float)(S_LEN - 1));
        offi[tid] = (int)cl;
    }
    __syncthreads();

    if (tid < N_SENT) {
        const int so   = offi[tid];
        const int eo   = offi[N_SENT + tid];
        const int base = tid * S_LEN;
        int si = min(base + so, T_LEN - S_LEN);            // clip(base+so, 0, T-L), so>=0
        int ei = min(max(base + S_LEN + eo, si), T_LEN);   // clip(base+L+eo, si, T)
        sidx[b * N_SENT + tid] = si;
        eidx[b * N_SENT + tid] = ei;
    }
}

// -------- Kernel 3: gather rows (or zeros) --------
// block (192, 4): threadIdx.x = float4 index within a 768-float row,
// threadIdx.y = row within block. grid = B*S*L/4 blocks. 192 % 64 == 0 so each wave
// stays inside one row -> sidx/eidx loads are wave-uniform. Measured equal to an
// ILP=24 + nontemporal-store variant (round 4) -> at its mixed read/write floor.
__global__ void gather_rows(const float4* __restrict__ in4,
                            const int* __restrict__ sidx,
                            const int* __restrict__ eidx,
                            float4* __restrict__ out4) {
    const int row = blockIdx.x * 4 + threadIdx.y;   // b*S*L + s*L + j
    const int j = row & (S_LEN - 1);
    const int s = (row >> 6) & (N_SENT - 1);
    const int b = row >> 11;
    const int si = sidx[b * N_SENT + s];
    const int ei = eidx[b * N_SENT + s];
    float4 v = make_float4(0.f, 0.f, 0.f, 0.f);
    if (j < ei - si) {
        v = in4[((size_t)b * T_LEN + (si + j)) * E4 + threadIdx.x];
    }
    out4[(size_t)row * E4 + threadIdx.x] = v;   // always write (out is poisoned)
}

extern "C" void kernel_launch(void* const* d_in, const int* in_sizes, int n_in,
                              void* d_out, int out_size, void* d_ws, size_t ws_size,
                              hipStream_t stream) {
    const float4* in4 = (const float4*)d_in[0];  // [16, 2048, 768]
    const float*  W   = (const float*)d_in[1];   // [768, 64]
    const float*  bias= (const float*)d_in[2];   // [64]
    float4* out4 = (float4*)d_out;               // [16, 32, 64, 768]

    float4* partial4 = (float4*)d_ws;            // NCHUNK*BATCH*E4 float4 = 1.5 MB
    int* sidx = (int*)((char*)d_ws + (size_t)NCHUNK * BATCH * E4 * sizeof(float4));
    int* eidx = sidx + BATCH * N_SENT;

    pool_partial<<<dim3(BATCH, NCHUNK), 192, 0, stream>>>(in4, partial4);
    compute_idx<<<BATCH, 256, 0, stream>>>(partial4, W, bias, sidx, eidx);
    gather_rows<<<dim3(BATCH * N_SENT * S_LEN / 4), dim3(192, 4), 0, stream>>>(
        in4, sidx, eidx, (float4*)out4);
}